// Round 1
// baseline (667.622 us; speedup 1.0000x reference)
//
#include <hip/hip_runtime.h>
#include <math.h>

#define B_DIM 4096
#define K_DIM 4096
#define D_DIM 1024
#define NSPLIT 8
#define KRANGE (K_DIM / NSPLIT)   // 512

// ws byte offsets
#define WN_OFF   0         // w_norm  : K floats
#define RS_OFF   16384     // rel_sum : K floats
#define XN_OFF   32768     // x_norm  : B floats
#define PACT_OFF 49152     // pact    : B*NSPLIT floats
#define PIDX_OFF 180224    // pidx    : B*NSPLIT ints
#define IDX_OFF  311296    // idx_int : B ints
#define WIN_OFF  327680    // winner  : K ints
#define LP_OFF   344064    // loss partials: 256 doubles

// ---------------- prep: w_norm[k], rel_sum[k], x_norm[b] ----------------
__global__ __launch_bounds__(256) void prep_kernel(
    const float* __restrict__ x, const float* __restrict__ w,
    const float* __restrict__ rel,
    float* __restrict__ w_norm, float* __restrict__ rel_sum,
    float* __restrict__ x_norm) {
  int row  = blockIdx.x * 4 + (threadIdx.x >> 6);
  int lane = threadIdx.x & 63;
  if (row < K_DIM) {
    const float4* wr = (const float4*)(w   + (size_t)row * D_DIM);
    const float4* rr = (const float4*)(rel + (size_t)row * D_DIM);
    float s2 = 0.f, sr = 0.f;
#pragma unroll
    for (int q = 0; q < 4; ++q) {
      float4 wv = wr[lane + 64 * q];
      float4 rv = rr[lane + 64 * q];
      s2 += wv.x * wv.x + wv.y * wv.y + wv.z * wv.z + wv.w * wv.w;
      sr += rv.x + rv.y + rv.z + rv.w;
    }
    for (int m = 1; m < 64; m <<= 1) {
      s2 += __shfl_xor(s2, m, 64);
      sr += __shfl_xor(sr, m, 64);
    }
    if (lane == 0) { w_norm[row] = s2; rel_sum[row] = sr; }
  } else {
    int rb = row - K_DIM;
    const float4* xr = (const float4*)(x + (size_t)rb * D_DIM);
    float s2 = 0.f;
#pragma unroll
    for (int q = 0; q < 4; ++q) {
      float4 xv = xr[lane + 64 * q];
      s2 += xv.x * xv.x + xv.y * xv.y + xv.z * xv.z + xv.w * xv.w;
    }
    for (int m = 1; m < 64; m <<= 1) s2 += __shfl_xor(s2, m, 64);
    if (lane == 0) x_norm[rb] = s2;
  }
}

// ---------------- winner init ----------------
__global__ void winner_init(int* __restrict__ winner) {
  int k = blockIdx.x * 256 + threadIdx.x;
  if (k < K_DIM) winner[k] = -1;
}

// ---------------- distance GEMM + per-split argmax ----------------
// grid: (B/64, NSPLIT), block 256. Each block: 64 rows x KRANGE cols.
__global__ __launch_bounds__(256) void argmax_kernel(
    const float* __restrict__ x, const float* __restrict__ w,
    const float* __restrict__ w_norm, const float* __restrict__ rel_sum,
    const float* __restrict__ x_norm,
    float* __restrict__ pact, int* __restrict__ pidx) {
  __shared__ float xsT[16][68];   // [d][row], padded
  __shared__ float wsT[16][68];   // [d][col]
  const int tid = threadIdx.x;
  const int tx = tid & 15, ty = tid >> 4;
  const int row0 = blockIdx.x * 64;
  const int ks0  = blockIdx.y * KRANGE;

  float xn[4];
#pragma unroll
  for (int i = 0; i < 4; ++i) xn[i] = x_norm[row0 + ty * 4 + i];

  float bestA[4];
  int   bestI[4];
#pragma unroll
  for (int i = 0; i < 4; ++i) { bestA[i] = -INFINITY; bestI[i] = 0x7fffffff; }

  const int lr = tid >> 2;          // 0..63 (tile row)
  const int lc = (tid & 3) * 4;     // 0,4,8,12 (tile col, float4)

  for (int kc = 0; kc < KRANGE; kc += 64) {
    const int k0 = ks0 + kc;
    float acc[4][4];
#pragma unroll
    for (int i = 0; i < 4; ++i)
#pragma unroll
      for (int j = 0; j < 4; ++j) acc[i][j] = 0.f;

    for (int d0 = 0; d0 < D_DIM; d0 += 16) {
      float4 xv = *(const float4*)(x + (size_t)(row0 + lr) * D_DIM + d0 + lc);
      float4 wv = *(const float4*)(w + (size_t)(k0  + lr) * D_DIM + d0 + lc);
      __syncthreads();
      xsT[lc + 0][lr] = xv.x; xsT[lc + 1][lr] = xv.y;
      xsT[lc + 2][lr] = xv.z; xsT[lc + 3][lr] = xv.w;
      wsT[lc + 0][lr] = wv.x; wsT[lc + 1][lr] = wv.y;
      wsT[lc + 2][lr] = wv.z; wsT[lc + 3][lr] = wv.w;
      __syncthreads();
#pragma unroll
      for (int kk = 0; kk < 16; ++kk) {
        float4 av = *(const float4*)&xsT[kk][ty * 4];
        float4 bv = *(const float4*)&wsT[kk][tx * 4];
        float ar[4] = {av.x, av.y, av.z, av.w};
        float br[4] = {bv.x, bv.y, bv.z, bv.w};
#pragma unroll
        for (int i = 0; i < 4; ++i)
#pragma unroll
          for (int j = 0; j < 4; ++j)
            acc[i][j] = fmaf(ar[i], br[j], acc[i][j]);
      }
    }

    // activation + running argmax (same fp op order as reference)
#pragma unroll
    for (int j = 0; j < 4; ++j) {
      int k = k0 + tx * 4 + j;
      float rs = rel_sum[k];
      float wn = w_norm[k];
      float rs_d = rs * (1.0f / 1024.0f);   // rel_sum / D (exact)
#pragma unroll
      for (int i = 0; i < 4; ++i) {
        float dist = (xn[i] + wn) - 2.0f * acc[i][j];
        float dw   = dist * rs_d;
        float act  = rs / ((rs + dw) + 1e-7f);
        if (act > bestA[i] || (act == bestA[i] && k < bestI[i])) {
          bestA[i] = act; bestI[i] = k;
        }
      }
    }
  }

  // reduce across tx (lanes within wave); global first-index via smaller-idx tie-break
#pragma unroll
  for (int m = 1; m < 16; m <<= 1) {
#pragma unroll
    for (int i = 0; i < 4; ++i) {
      float oa = __shfl_xor(bestA[i], m, 64);
      int   oi = __shfl_xor(bestI[i], m, 64);
      if (oa > bestA[i] || (oa == bestA[i] && oi < bestI[i])) {
        bestA[i] = oa; bestI[i] = oi;
      }
    }
  }
  if (tx == 0) {
#pragma unroll
    for (int i = 0; i < 4; ++i) {
      int r = row0 + ty * 4 + i;
      pact[(size_t)r * NSPLIT + blockIdx.y] = bestA[i];
      pidx[(size_t)r * NSPLIT + blockIdx.y] = bestI[i];
    }
  }
}

// ---------------- combine splits -> idx ----------------
__global__ void combine_kernel(const float* __restrict__ pact,
                               const int* __restrict__ pidx,
                               int* __restrict__ idx_int,
                               float* __restrict__ out_idx) {
  int b = blockIdx.x * 256 + threadIdx.x;
  if (b >= B_DIM) return;
  float bA = -INFINITY; int bI = 0x7fffffff;
#pragma unroll
  for (int s = 0; s < NSPLIT; ++s) {
    float a = pact[(size_t)b * NSPLIT + s];
    int  i2 = pidx[(size_t)b * NSPLIT + s];
    if (a > bA || (a == bA && i2 < bI)) { bA = a; bI = i2; }
  }
  idx_int[b] = bI;
  out_idx[b] = (float)bI;
}

// ---------------- winner[k] = max b with idx[b]==k (last-write-wins) ----------------
__global__ void winner_kernel(const int* __restrict__ idx_int,
                              int* __restrict__ winner) {
  int b = blockIdx.x * 256 + threadIdx.x;
  if (b < B_DIM) atomicMax(&winner[idx_int[b]], b);
}

// ---------------- scatter update / pass-through ----------------
__global__ __launch_bounds__(256) void update_kernel(
    const float* __restrict__ x, const float* __restrict__ w,
    const float* __restrict__ ma, const float* __restrict__ rel,
    const int* __restrict__ winner,
    float* __restrict__ out_w, float* __restrict__ out_ma,
    float* __restrict__ out_rel) {
  const int k = blockIdx.x;
  const int t = threadIdx.x;
  const size_t ro = (size_t)k * D_DIM;
  const int bw = winner[k];
  if (bw < 0) {
    float4 a = ((const float4*)(w   + ro))[t];
    float4 b = ((const float4*)(ma  + ro))[t];
    float4 c = ((const float4*)(rel + ro))[t];
    ((float4*)(out_w   + ro))[t] = a;
    ((float4*)(out_ma  + ro))[t] = b;
    ((float4*)(out_rel + ro))[t] = c;
    return;
  }
  const float a_c = (float)(0.3 * 1e-4);          // LR*DSBETA as fp32
  const float omc = (float)(1.0 - 0.3 * 1e-4);    // 1-a as fp32
  float4 xv  = ((const float4*)(x  + (size_t)bw * D_DIM))[t];
  float4 wv4 = ((const float4*)(w  + ro))[t];
  float4 mav = ((const float4*)(ma + ro))[t];
  float4 nm;
  nm.x = a_c * fabsf(xv.x - wv4.x) + omc * mav.x;
  nm.y = a_c * fabsf(xv.y - wv4.y) + omc * mav.y;
  nm.z = a_c * fabsf(xv.z - wv4.z) + omc * mav.z;
  nm.w = a_c * fabsf(xv.w - wv4.w) + omc * mav.w;

  float tmx = fmaxf(fmaxf(nm.x, nm.y), fmaxf(nm.z, nm.w));
  float tmn = fminf(fminf(nm.x, nm.y), fminf(nm.z, nm.w));
  float tsm = nm.x + nm.y + nm.z + nm.w;
  for (int m = 1; m < 64; m <<= 1) {
    tmx = fmaxf(tmx, __shfl_xor(tmx, m, 64));
    tmn = fminf(tmn, __shfl_xor(tmn, m, 64));
    tsm += __shfl_xor(tsm, m, 64);
  }
  __shared__ float smx[4], smn[4], ssm[4];
  if ((t & 63) == 0) { smx[t >> 6] = tmx; smn[t >> 6] = tmn; ssm[t >> 6] = tsm; }
  __syncthreads();
  if (t == 0) {
    float m1 = fmaxf(fmaxf(smx[0], smx[1]), fmaxf(smx[2], smx[3]));
    float m2 = fminf(fminf(smn[0], smn[1]), fminf(smn[2], smn[3]));
    float s1 = ssm[0] + ssm[1] + ssm[2] + ssm[3];
    smx[0] = m1; smn[0] = m2; ssm[0] = s1;
  }
  __syncthreads();
  const float mx  = smx[0];
  const float mn  = smn[0];
  const float avg = ssm[0] * (1.0f / 1024.0f);
  const float den = 0.01f * (mx - mn);   // EPS_DS*(mx-mn)

  float4 rl;
  rl.x = 1.0f / (1.0f + expf((nm.x - avg) / den));
  rl.y = 1.0f / (1.0f + expf((nm.y - avg) / den));
  rl.z = 1.0f / (1.0f + expf((nm.z - avg) / den));
  rl.w = 1.0f / (1.0f + expf((nm.w - avg) / den));
  if (isnan(rl.x)) rl.x = 1.0f;
  if (isnan(rl.y)) rl.y = 1.0f;
  if (isnan(rl.z)) rl.z = 1.0f;
  if (isnan(rl.w)) rl.w = 1.0f;

  float4 nw;
  nw.x = wv4.x + 0.3f * (xv.x - wv4.x);
  nw.y = wv4.y + 0.3f * (xv.y - wv4.y);
  nw.z = wv4.z + 0.3f * (xv.z - wv4.z);
  nw.w = wv4.w + 0.3f * (xv.w - wv4.w);

  ((float4*)(out_w   + ro))[t] = nw;
  ((float4*)(out_ma  + ro))[t] = nm;
  ((float4*)(out_rel + ro))[t] = rl;
}

// ---------------- loss = LR * sum(x - w[idx]) / B ----------------
__global__ __launch_bounds__(256) void loss_partial(
    const float* __restrict__ x, const float* __restrict__ w,
    const int* __restrict__ idx_int, double* __restrict__ partials) {
  const int t = threadIdx.x;
  double acc = 0.0;
  for (int b = blockIdx.x; b < B_DIM; b += gridDim.x) {
    int k = idx_int[b];
    float4 xv = ((const float4*)(x + (size_t)b * D_DIM))[t];
    float4 wv = ((const float4*)(w + (size_t)k * D_DIM))[t];
    float s = (xv.x - wv.x) + (xv.y - wv.y) + (xv.z - wv.z) + (xv.w - wv.w);
    acc += (double)s;
  }
  for (int m = 1; m < 64; m <<= 1) acc += __shfl_xor(acc, m, 64);
  __shared__ double sa[4];
  if ((t & 63) == 0) sa[t >> 6] = acc;
  __syncthreads();
  if (t == 0) partials[blockIdx.x] = sa[0] + sa[1] + sa[2] + sa[3];
}

__global__ void loss_final(const double* __restrict__ partials,
                           float* __restrict__ out_loss) {
  const int t = threadIdx.x;
  double acc = partials[t];
  for (int m = 1; m < 64; m <<= 1) acc += __shfl_xor(acc, m, 64);
  __shared__ double sa[4];
  if ((t & 63) == 0) sa[t >> 6] = acc;
  __syncthreads();
  if (t == 0)
    out_loss[0] = (float)(0.3 * (sa[0] + sa[1] + sa[2] + sa[3]) / (double)B_DIM);
}

extern "C" void kernel_launch(void* const* d_in, const int* in_sizes, int n_in,
                              void* d_out, int out_size, void* d_ws, size_t ws_size,
                              hipStream_t stream) {
  const float* x   = (const float*)d_in[0];
  const float* w   = (const float*)d_in[1];
  const float* ma  = (const float*)d_in[2];
  const float* rel = (const float*)d_in[3];

  float* out      = (float*)d_out;
  float* out_loss = out;
  float* out_idx  = out + 1;
  float* out_w    = out + 1 + B_DIM;
  float* out_ma   = out_w  + (size_t)K_DIM * D_DIM;
  float* out_rel  = out_ma + (size_t)K_DIM * D_DIM;

  char* ws = (char*)d_ws;
  float*  w_norm  = (float*)(ws + WN_OFF);
  float*  rel_sum = (float*)(ws + RS_OFF);
  float*  x_norm  = (float*)(ws + XN_OFF);
  float*  pact    = (float*)(ws + PACT_OFF);
  int*    pidx    = (int*)  (ws + PIDX_OFF);
  int*    idx_int = (int*)  (ws + IDX_OFF);
  int*    winner  = (int*)  (ws + WIN_OFF);
  double* lparts  = (double*)(ws + LP_OFF);

  prep_kernel<<<(K_DIM + B_DIM) / 4, 256, 0, stream>>>(x, w, rel, w_norm, rel_sum, x_norm);
  winner_init<<<K_DIM / 256, 256, 0, stream>>>(winner);
  argmax_kernel<<<dim3(B_DIM / 64, NSPLIT), 256, 0, stream>>>(
      x, w, w_norm, rel_sum, x_norm, pact, pidx);
  combine_kernel<<<B_DIM / 256, 256, 0, stream>>>(pact, pidx, idx_int, out_idx);
  winner_kernel<<<B_DIM / 256, 256, 0, stream>>>(idx_int, winner);
  update_kernel<<<K_DIM, 256, 0, stream>>>(x, w, ma, rel, winner, out_w, out_ma, out_rel);
  loss_partial<<<256, 256, 0, stream>>>(x, w, idx_int, lparts);
  loss_final<<<1, 256, 0, stream>>>(lparts, out_loss);
}

// Round 2
// 277.245 us; speedup vs baseline: 2.4081x; 2.4081x over previous
//
#include <hip/hip_runtime.h>
#include <math.h>

#define B_DIM 4096
#define K_DIM 4096
#define D_DIM 1024

typedef unsigned int uint32;
typedef unsigned short ushort16_t;
typedef __attribute__((ext_vector_type(8))) short short8;
typedef __attribute__((ext_vector_type(4))) float f32x4;

// ---------------- fallback (old) path ws offsets ----------------
#define NSPLIT_OLD 8
#define KRANGE (K_DIM / NSPLIT_OLD)
#define WN_OFF   0
#define RS_OFF   16384
#define XN_OFF   32768
#define PACT_OFF 49152
#define PIDX_OFF 180224
#define IDX_OFF  311296
#define WIN_OFF  327680
#define LP_OFF   344064

// ---------------- MFMA path ws offsets (bytes) ----------------
#define M_XH    0u
#define M_XL    8388608u
#define M_WH    16777216u
#define M_WL    25165824u
#define M_SMALL 33554432u
#define M_WN    (M_SMALL + 0u)
#define M_RS    (M_SMALL + 16384u)
#define M_XN    (M_SMALL + 32768u)
#define M_PACT  (M_SMALL + 49152u)      // 4096*32*4 = 524288
#define M_PIDX  (M_SMALL + 573440u)     // 524288
#define M_IDX   (M_SMALL + 1097728u)
#define M_WIN   (M_SMALL + 1114112u)
#define M_LP    (M_SMALL + 1130496u)
#define M_NEED  (M_SMALL + 1132544u)

// ---------------- helpers ----------------
__device__ __forceinline__ unsigned short f2bf(float f) {
  uint32 u = __float_as_uint(f);
  uint32 r = (u + 0x7fffu + ((u >> 16) & 1u)) >> 16;
  return (unsigned short)r;
}
__device__ __forceinline__ float bf2f(unsigned short h) {
  return __uint_as_float(((uint32)h) << 16);
}

typedef const __attribute__((address_space(1))) void gvoid_t;
typedef __attribute__((address_space(3))) void svoid_t;
__device__ __forceinline__ void async_copy16(const unsigned short* g, const short* l) {
  __builtin_amdgcn_global_load_lds((gvoid_t*)g, (svoid_t*)l, 16, 0, 0);
}

// ---------------- convert: fp32 -> bf16 hi/lo splits ----------------
// 8M floats total (x then w), 4 per thread.
__global__ __launch_bounds__(256) void convert_kernel(
    const float* __restrict__ x, const float* __restrict__ w,
    unsigned short* __restrict__ xh, unsigned short* __restrict__ xl,
    unsigned short* __restrict__ wh, unsigned short* __restrict__ wl) {
  size_t t = (size_t)blockIdx.x * 256 + threadIdx.x;   // float4 index, 0..2M
  const bool isw = t >= (size_t)(B_DIM * D_DIM / 4);
  size_t f4 = isw ? t - (size_t)(B_DIM * D_DIM / 4) : t;
  const float4* src = (const float4*)(isw ? w : x);
  unsigned short* hi = isw ? wh : xh;
  unsigned short* lo = isw ? wl : xl;
  float4 v = src[f4];
  unsigned short h0 = f2bf(v.x), h1 = f2bf(v.y), h2 = f2bf(v.z), h3 = f2bf(v.w);
  unsigned short l0 = f2bf(v.x - bf2f(h0));
  unsigned short l1 = f2bf(v.y - bf2f(h1));
  unsigned short l2 = f2bf(v.z - bf2f(h2));
  unsigned short l3 = f2bf(v.w - bf2f(h3));
  ushort4 hv; hv.x = h0; hv.y = h1; hv.z = h2; hv.w = h3;
  ushort4 lv; lv.x = l0; lv.y = l1; lv.z = l2; lv.w = l3;
  ((ushort4*)hi)[f4] = hv;
  ((ushort4*)lo)[f4] = lv;
}

// ---------------- prep: w_norm[k], rel_sum[k], x_norm[b] ----------------
__global__ __launch_bounds__(256) void prep_kernel(
    const float* __restrict__ x, const float* __restrict__ w,
    const float* __restrict__ rel,
    float* __restrict__ w_norm, float* __restrict__ rel_sum,
    float* __restrict__ x_norm) {
  int row  = blockIdx.x * 4 + (threadIdx.x >> 6);
  int lane = threadIdx.x & 63;
  if (row < K_DIM) {
    const float4* wr = (const float4*)(w   + (size_t)row * D_DIM);
    const float4* rr = (const float4*)(rel + (size_t)row * D_DIM);
    float s2 = 0.f, sr = 0.f;
#pragma unroll
    for (int q = 0; q < 4; ++q) {
      float4 wv = wr[lane + 64 * q];
      float4 rv = rr[lane + 64 * q];
      s2 += wv.x * wv.x + wv.y * wv.y + wv.z * wv.z + wv.w * wv.w;
      sr += rv.x + rv.y + rv.z + rv.w;
    }
    for (int m = 1; m < 64; m <<= 1) {
      s2 += __shfl_xor(s2, m, 64);
      sr += __shfl_xor(sr, m, 64);
    }
    if (lane == 0) { w_norm[row] = s2; rel_sum[row] = sr; }
  } else {
    int rb = row - K_DIM;
    const float4* xr = (const float4*)(x + (size_t)rb * D_DIM);
    float s2 = 0.f;
#pragma unroll
    for (int q = 0; q < 4; ++q) {
      float4 xv = xr[lane + 64 * q];
      s2 += xv.x * xv.x + xv.y * xv.y + xv.z * xv.z + xv.w * xv.w;
    }
    for (int m = 1; m < 64; m <<= 1) s2 += __shfl_xor(s2, m, 64);
    if (lane == 0) x_norm[rb] = s2;
  }
}

__global__ void winner_init(int* __restrict__ winner) {
  int k = blockIdx.x * 256 + threadIdx.x;
  if (k < K_DIM) winner[k] = -1;
}

// ---------------- MFMA distance GEMM + fused argmax ----------------
// grid (B/128, K/128), block 256 (4 waves, 2x2 of 64x64).
__global__ __launch_bounds__(256) void mfma_argmax_kernel(
    const unsigned short* __restrict__ xh, const unsigned short* __restrict__ xl,
    const unsigned short* __restrict__ wh, const unsigned short* __restrict__ wl,
    const float* __restrict__ w_norm, const float* __restrict__ rel_sum,
    const float* __restrict__ x_norm,
    float* __restrict__ pact, int* __restrict__ pidx) {
  __shared__ __align__(16) short lds[16384];   // Ah|Al|Bh|Bl, each 128x32 bf16
  short* Ah = lds;
  short* Al = lds + 4096;
  short* Bh = lds + 8192;
  short* Bl = lds + 12288;

  const int tid    = threadIdx.x;
  const int wid    = tid >> 6;
  const int lane   = tid & 63;
  const int quad   = lane >> 4;
  const int l15    = lane & 15;
  const int wave_r = wid >> 1;
  const int wave_c = wid & 1;
  const int row0   = blockIdx.x * 128;
  const int col0   = blockIdx.y * 128;

  // staging lane geometry: chunk c = wid*2+t covers tile rows c*16..c*16+15
  const int srow = lane >> 2;                       // row within chunk
  const int skq  = (lane & 3) ^ ((lane >> 3) & 3);  // swizzled source k-quarter
  // fragment read swizzle (depends only on lane)
  const int fswz = quad ^ ((l15 >> 1) & 3);

  f32x4 acc[4][4];
#pragma unroll
  for (int i = 0; i < 4; ++i)
#pragma unroll
    for (int j = 0; j < 4; ++j)
#pragma unroll
      for (int r = 0; r < 4; ++r) acc[i][j][r] = 0.f;

  for (int k0 = 0; k0 < D_DIM; k0 += 32) {
    __syncthreads();
#pragma unroll
    for (int t = 0; t < 2; ++t) {
      const int c = wid * 2 + t;
      const int ra = row0 + c * 16 + srow;          // x row
      const int rb = col0 + c * 16 + srow;          // w row (code)
      const size_t ga = (size_t)ra * D_DIM + k0 + skq * 8;
      const size_t gb = (size_t)rb * D_DIM + k0 + skq * 8;
      const int ldso = c * 512;                     // shorts, wave-uniform
      async_copy16(xh + ga, Ah + ldso);
      async_copy16(xl + ga, Al + ldso);
      async_copy16(wh + gb, Bh + ldso);
      async_copy16(wl + gb, Bl + ldso);
    }
    __syncthreads();

    short8 ah[4], al[4], bh[4], bl[4];
#pragma unroll
    for (int f = 0; f < 4; ++f) {
      const int ra = wave_r * 64 + f * 16 + l15;
      const int oa = ra * 32 + fswz * 8;
      ah[f] = *(const short8*)(Ah + oa);
      al[f] = *(const short8*)(Al + oa);
      const int rb = wave_c * 64 + f * 16 + l15;
      const int ob = rb * 32 + fswz * 8;
      bh[f] = *(const short8*)(Bh + ob);
      bl[f] = *(const short8*)(Bl + ob);
    }
#pragma unroll
    for (int i = 0; i < 4; ++i)
#pragma unroll
      for (int j = 0; j < 4; ++j) {
        acc[i][j] = __builtin_amdgcn_mfma_f32_16x16x32_bf16(ah[i], bh[j], acc[i][j], 0, 0, 0);
        acc[i][j] = __builtin_amdgcn_mfma_f32_16x16x32_bf16(ah[i], bl[j], acc[i][j], 0, 0, 0);
        acc[i][j] = __builtin_amdgcn_mfma_f32_16x16x32_bf16(al[i], bh[j], acc[i][j], 0, 0, 0);
      }
  }

  // ---- epilogue: act + argmax over this block's 128 cols ----
  float xnv[4][4];
#pragma unroll
  for (int fi = 0; fi < 4; ++fi)
#pragma unroll
    for (int r = 0; r < 4; ++r)
      xnv[fi][r] = x_norm[row0 + wave_r * 64 + fi * 16 + quad * 4 + r];

  float bestA[4][4];
  int   bestI[4][4];
#pragma unroll
  for (int fi = 0; fi < 4; ++fi)
#pragma unroll
    for (int r = 0; r < 4; ++r) { bestA[fi][r] = -INFINITY; bestI[fi][r] = 0x7fffffff; }

#pragma unroll
  for (int fj = 0; fj < 4; ++fj) {
    const int k = col0 + wave_c * 64 + fj * 16 + l15;
    const float rs  = rel_sum[k];
    const float wn  = w_norm[k];
    const float rsd = rs * (1.0f / 1024.0f);
#pragma unroll
    for (int fi = 0; fi < 4; ++fi)
#pragma unroll
      for (int r = 0; r < 4; ++r) {
        float dist = (xnv[fi][r] + wn) - 2.0f * acc[fi][fj][r];
        float dw   = dist * rsd;
        float act  = rs / ((rs + dw) + 1e-7f);
        if (act > bestA[fi][r] || (act == bestA[fi][r] && k < bestI[fi][r])) {
          bestA[fi][r] = act; bestI[fi][r] = k;
        }
      }
  }

  // reduce across the 16 lanes of each quad (same rows, different cols)
#pragma unroll
  for (int m = 1; m < 16; m <<= 1) {
#pragma unroll
    for (int fi = 0; fi < 4; ++fi)
#pragma unroll
      for (int r = 0; r < 4; ++r) {
        float oa = __shfl_xor(bestA[fi][r], m, 64);
        int   oi = __shfl_xor(bestI[fi][r], m, 64);
        if (oa > bestA[fi][r] || (oa == bestA[fi][r] && oi < bestI[fi][r])) {
          bestA[fi][r] = oa; bestI[fi][r] = oi;
        }
      }
  }

  __syncthreads();   // done with tile LDS; reuse for reduction
  float* sAct = (float*)lds;           // [2][128]
  int*   sIdx = (int*)(lds + 1024);    // [2][128] (offset 2048 B)
  if (l15 == 0) {
#pragma unroll
    for (int fi = 0; fi < 4; ++fi)
#pragma unroll
      for (int r = 0; r < 4; ++r) {
        int row_local = wave_r * 64 + fi * 16 + quad * 4 + r;
        sAct[wave_c * 128 + row_local] = bestA[fi][r];
        sIdx[wave_c * 128 + row_local] = bestI[fi][r];
      }
  }
  __syncthreads();
  if (tid < 128) {
    float a0 = sAct[tid],       a1 = sAct[128 + tid];
    int   i0 = sIdx[tid],       i1 = sIdx[128 + tid];
    float ba = a0; int bi = i0;
    if (a1 > ba) { ba = a1; bi = i1; }     // tie -> half 0 (smaller k) correct
    pact[(size_t)(row0 + tid) * 32 + blockIdx.y] = ba;
    pidx[(size_t)(row0 + tid) * 32 + blockIdx.y] = bi;
  }
}

// ---------------- fallback vector-ALU argmax (old path) ----------------
__global__ __launch_bounds__(256) void argmax_kernel(
    const float* __restrict__ x, const float* __restrict__ w,
    const float* __restrict__ w_norm, const float* __restrict__ rel_sum,
    const float* __restrict__ x_norm,
    float* __restrict__ pact, int* __restrict__ pidx) {
  __shared__ float xsT[16][68];
  __shared__ float wsT[16][68];
  const int tid = threadIdx.x;
  const int tx = tid & 15, ty = tid >> 4;
  const int row0 = blockIdx.x * 64;
  const int ks0  = blockIdx.y * KRANGE;

  float xn[4];
#pragma unroll
  for (int i = 0; i < 4; ++i) xn[i] = x_norm[row0 + ty * 4 + i];
  float bestA[4]; int bestI[4];
#pragma unroll
  for (int i = 0; i < 4; ++i) { bestA[i] = -INFINITY; bestI[i] = 0x7fffffff; }
  const int lr = tid >> 2;
  const int lc = (tid & 3) * 4;

  for (int kc = 0; kc < KRANGE; kc += 64) {
    const int k0 = ks0 + kc;
    float acc[4][4];
#pragma unroll
    for (int i = 0; i < 4; ++i)
#pragma unroll
      for (int j = 0; j < 4; ++j) acc[i][j] = 0.f;
    for (int d0 = 0; d0 < D_DIM; d0 += 16) {
      float4 xv = *(const float4*)(x + (size_t)(row0 + lr) * D_DIM + d0 + lc);
      float4 wv = *(const float4*)(w + (size_t)(k0  + lr) * D_DIM + d0 + lc);
      __syncthreads();
      xsT[lc + 0][lr] = xv.x; xsT[lc + 1][lr] = xv.y;
      xsT[lc + 2][lr] = xv.z; xsT[lc + 3][lr] = xv.w;
      wsT[lc + 0][lr] = wv.x; wsT[lc + 1][lr] = wv.y;
      wsT[lc + 2][lr] = wv.z; wsT[lc + 3][lr] = wv.w;
      __syncthreads();
#pragma unroll
      for (int kk = 0; kk < 16; ++kk) {
        float4 av = *(const float4*)&xsT[kk][ty * 4];
        float4 bv = *(const float4*)&wsT[kk][tx * 4];
        float ar[4] = {av.x, av.y, av.z, av.w};
        float br[4] = {bv.x, bv.y, bv.z, bv.w};
#pragma unroll
        for (int i = 0; i < 4; ++i)
#pragma unroll
          for (int j = 0; j < 4; ++j)
            acc[i][j] = fmaf(ar[i], br[j], acc[i][j]);
      }
    }
#pragma unroll
    for (int j = 0; j < 4; ++j) {
      int k = k0 + tx * 4 + j;
      float rs = rel_sum[k];
      float wn = w_norm[k];
      float rs_d = rs * (1.0f / 1024.0f);
#pragma unroll
      for (int i = 0; i < 4; ++i) {
        float dist = (xn[i] + wn) - 2.0f * acc[i][j];
        float dw   = dist * rs_d;
        float act  = rs / ((rs + dw) + 1e-7f);
        if (act > bestA[i] || (act == bestA[i] && k < bestI[i])) {
          bestA[i] = act; bestI[i] = k;
        }
      }
    }
  }
#pragma unroll
  for (int m = 1; m < 16; m <<= 1) {
#pragma unroll
    for (int i = 0; i < 4; ++i) {
      float oa = __shfl_xor(bestA[i], m, 64);
      int   oi = __shfl_xor(bestI[i], m, 64);
      if (oa > bestA[i] || (oa == bestA[i] && oi < bestI[i])) {
        bestA[i] = oa; bestI[i] = oi;
      }
    }
  }
  if (tx == 0) {
#pragma unroll
    for (int i = 0; i < 4; ++i) {
      int r = row0 + ty * 4 + i;
      pact[(size_t)r * NSPLIT_OLD + blockIdx.y] = bestA[i];
      pidx[(size_t)r * NSPLIT_OLD + blockIdx.y] = bestI[i];
    }
  }
}

// ---------------- combine splits -> idx ----------------
__global__ void combine_kernel(const float* __restrict__ pact,
                               const int* __restrict__ pidx,
                               int* __restrict__ idx_int,
                               float* __restrict__ out_idx, int nsplit) {
  int b = blockIdx.x * 256 + threadIdx.x;
  if (b >= B_DIM) return;
  float bA = -INFINITY; int bI = 0x7fffffff;
  for (int s = 0; s < nsplit; ++s) {
    float a = pact[(size_t)b * nsplit + s];
    int  i2 = pidx[(size_t)b * nsplit + s];
    if (a > bA || (a == bA && i2 < bI)) { bA = a; bI = i2; }
  }
  idx_int[b] = bI;
  out_idx[b] = (float)bI;
}

__global__ void winner_kernel(const int* __restrict__ idx_int,
                              int* __restrict__ winner) {
  int b = blockIdx.x * 256 + threadIdx.x;
  if (b < B_DIM) atomicMax(&winner[idx_int[b]], b);
}

// ---------------- scatter update / pass-through ----------------
__global__ __launch_bounds__(256) void update_kernel(
    const float* __restrict__ x, const float* __restrict__ w,
    const float* __restrict__ ma, const float* __restrict__ rel,
    const int* __restrict__ winner,
    float* __restrict__ out_w, float* __restrict__ out_ma,
    float* __restrict__ out_rel) {
  const int k = blockIdx.x;
  const int t = threadIdx.x;
  const size_t ro = (size_t)k * D_DIM;
  const int bw = winner[k];
  if (bw < 0) {
    float4 a = ((const float4*)(w   + ro))[t];
    float4 b = ((const float4*)(ma  + ro))[t];
    float4 c = ((const float4*)(rel + ro))[t];
    ((float4*)(out_w   + ro))[t] = a;
    ((float4*)(out_ma  + ro))[t] = b;
    ((float4*)(out_rel + ro))[t] = c;
    return;
  }
  const float a_c = (float)(0.3 * 1e-4);
  const float omc = (float)(1.0 - 0.3 * 1e-4);
  float4 xv  = ((const float4*)(x  + (size_t)bw * D_DIM))[t];
  float4 wv4 = ((const float4*)(w  + ro))[t];
  float4 mav = ((const float4*)(ma + ro))[t];
  float4 nm;
  nm.x = a_c * fabsf(xv.x - wv4.x) + omc * mav.x;
  nm.y = a_c * fabsf(xv.y - wv4.y) + omc * mav.y;
  nm.z = a_c * fabsf(xv.z - wv4.z) + omc * mav.z;
  nm.w = a_c * fabsf(xv.w - wv4.w) + omc * mav.w;

  float tmx = fmaxf(fmaxf(nm.x, nm.y), fmaxf(nm.z, nm.w));
  float tmn = fminf(fminf(nm.x, nm.y), fminf(nm.z, nm.w));
  float tsm = nm.x + nm.y + nm.z + nm.w;
  for (int m = 1; m < 64; m <<= 1) {
    tmx = fmaxf(tmx, __shfl_xor(tmx, m, 64));
    tmn = fminf(tmn, __shfl_xor(tmn, m, 64));
    tsm += __shfl_xor(tsm, m, 64);
  }
  __shared__ float smx[4], smn[4], ssm[4];
  if ((t & 63) == 0) { smx[t >> 6] = tmx; smn[t >> 6] = tmn; ssm[t >> 6] = tsm; }
  __syncthreads();
  if (t == 0) {
    float m1 = fmaxf(fmaxf(smx[0], smx[1]), fmaxf(smx[2], smx[3]));
    float m2 = fminf(fminf(smn[0], smn[1]), fminf(smn[2], smn[3]));
    float s1 = ssm[0] + ssm[1] + ssm[2] + ssm[3];
    smx[0] = m1; smn[0] = m2; ssm[0] = s1;
  }
  __syncthreads();
  const float mx  = smx[0];
  const float mn  = smn[0];
  const float avg = ssm[0] * (1.0f / 1024.0f);
  const float den = 0.01f * (mx - mn);

  float4 rl;
  rl.x = 1.0f / (1.0f + expf((nm.x - avg) / den));
  rl.y = 1.0f / (1.0f + expf((nm.y - avg) / den));
  rl.z = 1.0f / (1.0f + expf((nm.z - avg) / den));
  rl.w = 1.0f / (1.0f + expf((nm.w - avg) / den));
  if (isnan(rl.x)) rl.x = 1.0f;
  if (isnan(rl.y)) rl.y = 1.0f;
  if (isnan(rl.z)) rl.z = 1.0f;
  if (isnan(rl.w)) rl.w = 1.0f;

  float4 nw;
  nw.x = wv4.x + 0.3f * (xv.x - wv4.x);
  nw.y = wv4.y + 0.3f * (xv.y - wv4.y);
  nw.z = wv4.z + 0.3f * (xv.z - wv4.z);
  nw.w = wv4.w + 0.3f * (xv.w - wv4.w);

  ((float4*)(out_w   + ro))[t] = nw;
  ((float4*)(out_ma  + ro))[t] = nm;
  ((float4*)(out_rel + ro))[t] = rl;
}

// ---------------- loss ----------------
__global__ __launch_bounds__(256) void loss_partial(
    const float* __restrict__ x, const float* __restrict__ w,
    const int* __restrict__ idx_int, double* __restrict__ partials) {
  const int t = threadIdx.x;
  double acc = 0.0;
  for (int b = blockIdx.x; b < B_DIM; b += gridDim.x) {
    int k = idx_int[b];
    float4 xv = ((const float4*)(x + (size_t)b * D_DIM))[t];
    float4 wv = ((const float4*)(w + (size_t)k * D_DIM))[t];
    float s = (xv.x - wv.x) + (xv.y - wv.y) + (xv.z - wv.z) + (xv.w - wv.w);
    acc += (double)s;
  }
  for (int m = 1; m < 64; m <<= 1) acc += __shfl_xor(acc, m, 64);
  __shared__ double sa[4];
  if ((t & 63) == 0) sa[t >> 6] = acc;
  __syncthreads();
  if (t == 0) partials[blockIdx.x] = sa[0] + sa[1] + sa[2] + sa[3];
}

__global__ void loss_final(const double* __restrict__ partials,
                           float* __restrict__ out_loss) {
  const int t = threadIdx.x;
  double acc = partials[t];
  for (int m = 1; m < 64; m <<= 1) acc += __shfl_xor(acc, m, 64);
  __shared__ double sa[4];
  if ((t & 63) == 0) sa[t >> 6] = acc;
  __syncthreads();
  if (t == 0)
    out_loss[0] = (float)(0.3 * (sa[0] + sa[1] + sa[2] + sa[3]) / (double)B_DIM);
}

extern "C" void kernel_launch(void* const* d_in, const int* in_sizes, int n_in,
                              void* d_out, int out_size, void* d_ws, size_t ws_size,
                              hipStream_t stream) {
  const float* x   = (const float*)d_in[0];
  const float* w   = (const float*)d_in[1];
  const float* ma  = (const float*)d_in[2];
  const float* rel = (const float*)d_in[3];

  float* out      = (float*)d_out;
  float* out_loss = out;
  float* out_idx  = out + 1;
  float* out_w    = out + 1 + B_DIM;
  float* out_ma   = out_w  + (size_t)K_DIM * D_DIM;
  float* out_rel  = out_ma + (size_t)K_DIM * D_DIM;

  char* ws = (char*)d_ws;

  if (ws_size >= (size_t)M_NEED) {
    // -------- MFMA path --------
    unsigned short* xh = (unsigned short*)(ws + M_XH);
    unsigned short* xl = (unsigned short*)(ws + M_XL);
    unsigned short* whp = (unsigned short*)(ws + M_WH);
    unsigned short* wlp = (unsigned short*)(ws + M_WL);
    float*  w_norm  = (float*)(ws + M_WN);
    float*  rel_sum = (float*)(ws + M_RS);
    float*  x_norm  = (float*)(ws + M_XN);
    float*  pact    = (float*)(ws + M_PACT);
    int*    pidx    = (int*)  (ws + M_PIDX);
    int*    idx_int = (int*)  (ws + M_IDX);
    int*    winner  = (int*)  (ws + M_WIN);
    double* lparts  = (double*)(ws + M_LP);

    convert_kernel<<<(B_DIM + K_DIM) * D_DIM / 4 / 256, 256, 0, stream>>>(
        x, w, xh, xl, whp, wlp);
    prep_kernel<<<(K_DIM + B_DIM) / 4, 256, 0, stream>>>(x, w, rel, w_norm, rel_sum, x_norm);
    winner_init<<<K_DIM / 256, 256, 0, stream>>>(winner);
    mfma_argmax_kernel<<<dim3(B_DIM / 128, K_DIM / 128), 256, 0, stream>>>(
        xh, xl, whp, wlp, w_norm, rel_sum, x_norm, pact, pidx);
    combine_kernel<<<B_DIM / 256, 256, 0, stream>>>(pact, pidx, idx_int, out_idx, 32);
    winner_kernel<<<B_DIM / 256, 256, 0, stream>>>(idx_int, winner);
    update_kernel<<<K_DIM, 256, 0, stream>>>(x, w, ma, rel, winner, out_w, out_ma, out_rel);
    loss_partial<<<256, 256, 0, stream>>>(x, w, idx_int, lparts);
    loss_final<<<1, 256, 0, stream>>>(lparts, out_loss);
  } else {
    // -------- fallback (round-1) path --------
    float*  w_norm  = (float*)(ws + WN_OFF);
    float*  rel_sum = (float*)(ws + RS_OFF);
    float*  x_norm  = (float*)(ws + XN_OFF);
    float*  pact    = (float*)(ws + PACT_OFF);
    int*    pidx    = (int*)  (ws + PIDX_OFF);
    int*    idx_int = (int*)  (ws + IDX_OFF);
    int*    winner  = (int*)  (ws + WIN_OFF);
    double* lparts  = (double*)(ws + LP_OFF);

    prep_kernel<<<(K_DIM + B_DIM) / 4, 256, 0, stream>>>(x, w, rel, w_norm, rel_sum, x_norm);
    winner_init<<<K_DIM / 256, 256, 0, stream>>>(winner);
    argmax_kernel<<<dim3(B_DIM / 64, NSPLIT_OLD), 256, 0, stream>>>(
        x, w, w_norm, rel_sum, x_norm, pact, pidx);
    combine_kernel<<<B_DIM / 256, 256, 0, stream>>>(pact, pidx, idx_int, out_idx, NSPLIT_OLD);
    winner_kernel<<<B_DIM / 256, 256, 0, stream>>>(idx_int, winner);
    update_kernel<<<K_DIM, 256, 0, stream>>>(x, w, ma, rel, winner, out_w, out_ma, out_rel);
    loss_partial<<<256, 256, 0, stream>>>(x, w, idx_int, lparts);
    loss_final<<<1, 256, 0, stream>>>(lparts, out_loss);
  }
}

// Round 3
// 226.007 us; speedup vs baseline: 2.9540x; 1.2267x over previous
//
#include <hip/hip_runtime.h>
#include <math.h>

#define B_DIM 4096
#define K_DIM 4096
#define D_DIM 1024

typedef unsigned int uint32;
typedef __attribute__((ext_vector_type(8))) short short8;
typedef __attribute__((ext_vector_type(4))) float f32x4;

#define W_ACT 4.0e-4f
#define ACT_SPLIT 3072   // rows < ACT_SPLIT live in d_out region, rest in ws

// ---------------- new-path ws offsets (bytes) ----------------
#define N_XH    0u
#define N_WH    8388608u
#define N_ACTHI 16777216u                 // 1024 rows * 4096 * 4B
#define N_SMALL 33554432u
#define N_WN    (N_SMALL + 0u)
#define N_RS    (N_SMALL + 16384u)
#define N_XN    (N_SMALL + 32768u)
#define N_PACT  (N_SMALL + 49152u)        // 4096*32*4 = 524288
#define N_RMX   (N_SMALL + 573440u)
#define N_IDX   (N_SMALL + 589824u)
#define N_WIN   (N_SMALL + 606208u)
#define N_LP    (N_SMALL + 622592u)
#define N_NEED  (N_SMALL + 624640u)       // 34,179,072

// ---------------- fallback (round-1) ws offsets ----------------
#define NSPLIT_OLD 8
#define KRANGE (K_DIM / NSPLIT_OLD)
#define WN_OFF   0
#define RS_OFF   16384
#define XN_OFF   32768
#define PACT_OFF 49152
#define PIDX_OFF 180224
#define IDX_OFF  311296
#define WIN_OFF  327680
#define LP_OFF   344064

// ---------------- helpers ----------------
__device__ __forceinline__ unsigned short f2bf(float f) {
  uint32 u = __float_as_uint(f);
  uint32 r = (u + 0x7fffu + ((u >> 16) & 1u)) >> 16;
  return (unsigned short)r;
}

typedef const __attribute__((address_space(1))) void gvoid_t;
typedef __attribute__((address_space(3))) void svoid_t;
__device__ __forceinline__ void async_copy16(const unsigned short* g, const short* l) {
  __builtin_amdgcn_global_load_lds((gvoid_t*)g, (svoid_t*)l, 16, 0, 0);
}

// ---------------- prep+convert: norms, rel_sum, bf16-hi of x and w ----------------
__global__ __launch_bounds__(256) void prep_convert_kernel(
    const float* __restrict__ x, const float* __restrict__ w,
    const float* __restrict__ rel,
    unsigned short* __restrict__ xh, unsigned short* __restrict__ wh,
    float* __restrict__ w_norm, float* __restrict__ rel_sum,
    float* __restrict__ x_norm) {
  int row  = blockIdx.x * 4 + (threadIdx.x >> 6);
  int lane = threadIdx.x & 63;
  if (row < K_DIM) {
    const float4* wr = (const float4*)(w   + (size_t)row * D_DIM);
    const float4* rr = (const float4*)(rel + (size_t)row * D_DIM);
    ushort4* hp = (ushort4*)(wh + (size_t)row * D_DIM);
    float s2 = 0.f, sr = 0.f;
#pragma unroll
    for (int q = 0; q < 4; ++q) {
      float4 wv = wr[lane + 64 * q];
      float4 rv = rr[lane + 64 * q];
      s2 += wv.x * wv.x + wv.y * wv.y + wv.z * wv.z + wv.w * wv.w;
      sr += rv.x + rv.y + rv.z + rv.w;
      ushort4 hv;
      hv.x = f2bf(wv.x); hv.y = f2bf(wv.y); hv.z = f2bf(wv.z); hv.w = f2bf(wv.w);
      hp[lane + 64 * q] = hv;
    }
    for (int m = 1; m < 64; m <<= 1) {
      s2 += __shfl_xor(s2, m, 64);
      sr += __shfl_xor(sr, m, 64);
    }
    if (lane == 0) { w_norm[row] = s2; rel_sum[row] = sr; }
  } else {
    int rb = row - K_DIM;
    const float4* xr = (const float4*)(x + (size_t)rb * D_DIM);
    ushort4* hp = (ushort4*)(xh + (size_t)rb * D_DIM);
    float s2 = 0.f;
#pragma unroll
    for (int q = 0; q < 4; ++q) {
      float4 xv = xr[lane + 64 * q];
      s2 += xv.x * xv.x + xv.y * xv.y + xv.z * xv.z + xv.w * xv.w;
      ushort4 hv;
      hv.x = f2bf(xv.x); hv.y = f2bf(xv.y); hv.z = f2bf(xv.z); hv.w = f2bf(xv.w);
      hp[lane + 64 * q] = hv;
    }
    for (int m = 1; m < 64; m <<= 1) s2 += __shfl_xor(s2, m, 64);
    if (lane == 0) x_norm[rb] = s2;
  }
}

__global__ void winner_init(int* __restrict__ winner) {
  int k = blockIdx.x * 256 + threadIdx.x;
  if (k < K_DIM) winner[k] = -1;
}

// ---------------- Pass A: bf16 hi-hi GEMM -> approx act matrix + row/block maxima ----
// grid (B/128, K/128), block 256 (4 waves, 2x2 of 64x64).
__global__ __launch_bounds__(256) void mfma_act_kernel(
    const unsigned short* __restrict__ xh, const unsigned short* __restrict__ wh,
    const float* __restrict__ w_norm, const float* __restrict__ rel_sum,
    const float* __restrict__ x_norm,
    float* __restrict__ act_lo, float* __restrict__ act_hi,
    float* __restrict__ pact) {
  __shared__ __align__(16) short lds[8192];   // Ah|Bh, each 128x32 bf16
  short* Ah = lds;
  short* Bh = lds + 4096;

  const int tid    = threadIdx.x;
  const int wid    = tid >> 6;
  const int lane   = tid & 63;
  const int quad   = lane >> 4;
  const int l15    = lane & 15;
  const int wave_r = wid >> 1;
  const int wave_c = wid & 1;
  const int row0   = blockIdx.x * 128;
  const int col0   = blockIdx.y * 128;

  const int srow = lane >> 2;
  const int skq  = (lane & 3) ^ ((lane >> 3) & 3);
  const int fswz = quad ^ ((l15 >> 1) & 3);

  f32x4 acc[4][4];
#pragma unroll
  for (int i = 0; i < 4; ++i)
#pragma unroll
    for (int j = 0; j < 4; ++j)
#pragma unroll
      for (int r = 0; r < 4; ++r) acc[i][j][r] = 0.f;

  for (int k0 = 0; k0 < D_DIM; k0 += 32) {
    __syncthreads();
#pragma unroll
    for (int t = 0; t < 2; ++t) {
      const int c = wid * 2 + t;
      const size_t ga = (size_t)(row0 + c * 16 + srow) * D_DIM + k0 + skq * 8;
      const size_t gb = (size_t)(col0 + c * 16 + srow) * D_DIM + k0 + skq * 8;
      async_copy16(xh + ga, Ah + c * 512);
      async_copy16(wh + gb, Bh + c * 512);
    }
    __syncthreads();

    short8 af[4], bf[4];
#pragma unroll
    for (int f = 0; f < 4; ++f) {
      af[f] = *(const short8*)(Ah + (wave_r * 64 + f * 16 + l15) * 32 + fswz * 8);
      bf[f] = *(const short8*)(Bh + (wave_c * 64 + f * 16 + l15) * 32 + fswz * 8);
    }
#pragma unroll
    for (int i = 0; i < 4; ++i)
#pragma unroll
      for (int j = 0; j < 4; ++j)
        acc[i][j] = __builtin_amdgcn_mfma_f32_16x16x32_bf16(af[i], bf[j], acc[i][j], 0, 0, 0);
  }

  // ---- epilogue: act + full store + per-row block max ----
  float xnv[4][4];
#pragma unroll
  for (int fi = 0; fi < 4; ++fi)
#pragma unroll
    for (int r = 0; r < 4; ++r)
      xnv[fi][r] = x_norm[row0 + wave_r * 64 + fi * 16 + quad * 4 + r];

  float bestA[4][4];
#pragma unroll
  for (int fi = 0; fi < 4; ++fi)
#pragma unroll
    for (int r = 0; r < 4; ++r) bestA[fi][r] = -INFINITY;

#pragma unroll
  for (int fj = 0; fj < 4; ++fj) {
    const int k = col0 + wave_c * 64 + fj * 16 + l15;
    const float rs  = rel_sum[k];
    const float wn  = w_norm[k];
    const float rsd = rs * (1.0f / 1024.0f);
#pragma unroll
    for (int fi = 0; fi < 4; ++fi)
#pragma unroll
      for (int r = 0; r < 4; ++r) {
        float dist = (xnv[fi][r] + wn) - 2.0f * acc[fi][fj][r];
        float dw   = dist * rsd;
        float act  = rs / ((rs + dw) + 1e-7f);
        int grow = row0 + wave_r * 64 + fi * 16 + quad * 4 + r;
        float* ab = (grow < ACT_SPLIT)
                        ? act_lo + (size_t)grow * K_DIM + k
                        : act_hi + (size_t)(grow - ACT_SPLIT) * K_DIM + k;
        *ab = act;
        bestA[fi][r] = fmaxf(bestA[fi][r], act);
      }
  }

#pragma unroll
  for (int m = 1; m < 16; m <<= 1)
#pragma unroll
    for (int fi = 0; fi < 4; ++fi)
#pragma unroll
      for (int r = 0; r < 4; ++r)
        bestA[fi][r] = fmaxf(bestA[fi][r], __shfl_xor(bestA[fi][r], m, 64));

  __syncthreads();
  float* sAct = (float*)lds;   // [2][128]
  if (l15 == 0) {
#pragma unroll
    for (int fi = 0; fi < 4; ++fi)
#pragma unroll
      for (int r = 0; r < 4; ++r)
        sAct[wave_c * 128 + wave_r * 64 + fi * 16 + quad * 4 + r] = bestA[fi][r];
  }
  __syncthreads();
  if (tid < 128)
    pact[(size_t)(row0 + tid) * 32 + blockIdx.y] = fmaxf(sAct[tid], sAct[128 + tid]);
}

// ---------------- rowmax over 32 block partials ----------------
__global__ void rowmax_kernel(const float* __restrict__ pact,
                              float* __restrict__ rowmax) {
  int b = blockIdx.x * 256 + threadIdx.x;
  if (b >= B_DIM) return;
  float m = -INFINITY;
#pragma unroll
  for (int s = 0; s < 32; ++s) m = fmaxf(m, pact[(size_t)b * 32 + s]);
  rowmax[b] = m;
}

// ---------------- Pass B: scan + exact refinement ----------------
// one block (256 thr) per row b
__global__ __launch_bounds__(256) void scan_refine_kernel(
    const float* __restrict__ act_lo, const float* __restrict__ act_hi,
    const float* __restrict__ rowmax,
    const float* __restrict__ x, const float* __restrict__ w,
    const float* __restrict__ w_norm, const float* __restrict__ rel_sum,
    const float* __restrict__ x_norm,
    int* __restrict__ idx_int, float* __restrict__ out_idx,
    int* __restrict__ winner) {
  const int b = blockIdx.x;
  const int t = threadIdx.x;
  const float* arow = (b < ACT_SPLIT)
                          ? act_lo + (size_t)b * K_DIM
                          : act_hi + (size_t)(b - ACT_SPLIT) * K_DIM;
  const float thr = rowmax[b] - W_ACT;

  __shared__ int cnt;
  __shared__ int cand[256];
  __shared__ float cdot[256];
  if (t == 0) cnt = 0;
  __syncthreads();

  // scalar (4B-aligned) coalesced reads
#pragma unroll
  for (int e = 0; e < 16; ++e) {
    int k = t + 256 * e;
    float v = arow[k];
    if (v >= thr) {
      int p = atomicAdd(&cnt, 1);
      cand[p & 255] = k;
    }
  }
  __syncthreads();
  int n = cnt < 256 ? cnt : 256;

  // refine: one wave per candidate (round-robin)
  const int wv = t >> 6, ln = t & 63;
  const float4* xr = (const float4*)(x + (size_t)b * D_DIM);
  float4 xv[4];
#pragma unroll
  for (int q = 0; q < 4; ++q) xv[q] = xr[ln + 64 * q];
  for (int c = wv; c < n; c += 4) {
    int k = cand[c];
    const float4* wr = (const float4*)(w + (size_t)k * D_DIM);
    float s = 0.f;
#pragma unroll
    for (int q = 0; q < 4; ++q) {
      float4 wv4 = wr[ln + 64 * q];
      s += xv[q].x * wv4.x + xv[q].y * wv4.y + xv[q].z * wv4.z + xv[q].w * wv4.w;
    }
    for (int m = 1; m < 64; m <<= 1) s += __shfl_xor(s, m, 64);
    if (ln == 0) cdot[c] = s;
  }
  __syncthreads();

  if (t == 0) {
    const float xn = x_norm[b];
    float bA = -INFINITY;
    int bI = 0x7fffffff;
    for (int c = 0; c < n; ++c) {
      int k = cand[c];
      float rs = rel_sum[k];
      float wn = w_norm[k];
      float dist = (xn + wn) - 2.0f * cdot[c];
      float dw   = dist * (rs * (1.0f / 1024.0f));
      float act  = rs / ((rs + dw) + 1e-7f);
      if (act > bA || (act == bA && k < bI)) { bA = act; bI = k; }
    }
    idx_int[b] = bI;
    out_idx[b] = (float)bI;
    atomicMax(&winner[bI], b);
  }
}

// ---------------- scatter update / pass-through ----------------
__global__ __launch_bounds__(256) void update_kernel(
    const float* __restrict__ x, const float* __restrict__ w,
    const float* __restrict__ ma, const float* __restrict__ rel,
    const int* __restrict__ winner,
    float* __restrict__ out_w, float* __restrict__ out_ma,
    float* __restrict__ out_rel) {
  const int k = blockIdx.x;
  const int t = threadIdx.x;
  const size_t ro = (size_t)k * D_DIM;
  const int bw = winner[k];
  if (bw < 0) {
    float4 a = ((const float4*)(w   + ro))[t];
    float4 b = ((const float4*)(ma  + ro))[t];
    float4 c = ((const float4*)(rel + ro))[t];
    ((float4*)(out_w   + ro))[t] = a;
    ((float4*)(out_ma  + ro))[t] = b;
    ((float4*)(out_rel + ro))[t] = c;
    return;
  }
  const float a_c = (float)(0.3 * 1e-4);
  const float omc = (float)(1.0 - 0.3 * 1e-4);
  float4 xv  = ((const float4*)(x  + (size_t)bw * D_DIM))[t];
  float4 wv4 = ((const float4*)(w  + ro))[t];
  float4 mav = ((const float4*)(ma + ro))[t];
  float4 nm;
  nm.x = a_c * fabsf(xv.x - wv4.x) + omc * mav.x;
  nm.y = a_c * fabsf(xv.y - wv4.y) + omc * mav.y;
  nm.z = a_c * fabsf(xv.z - wv4.z) + omc * mav.z;
  nm.w = a_c * fabsf(xv.w - wv4.w) + omc * mav.w;

  float tmx = fmaxf(fmaxf(nm.x, nm.y), fmaxf(nm.z, nm.w));
  float tmn = fminf(fminf(nm.x, nm.y), fminf(nm.z, nm.w));
  float tsm = nm.x + nm.y + nm.z + nm.w;
  for (int m = 1; m < 64; m <<= 1) {
    tmx = fmaxf(tmx, __shfl_xor(tmx, m, 64));
    tmn = fminf(tmn, __shfl_xor(tmn, m, 64));
    tsm += __shfl_xor(tsm, m, 64);
  }
  __shared__ float smx[4], smn[4], ssm[4];
  if ((t & 63) == 0) { smx[t >> 6] = tmx; smn[t >> 6] = tmn; ssm[t >> 6] = tsm; }
  __syncthreads();
  if (t == 0) {
    float m1 = fmaxf(fmaxf(smx[0], smx[1]), fmaxf(smx[2], smx[3]));
    float m2 = fminf(fminf(smn[0], smn[1]), fminf(smn[2], smn[3]));
    float s1 = ssm[0] + ssm[1] + ssm[2] + ssm[3];
    smx[0] = m1; smn[0] = m2; ssm[0] = s1;
  }
  __syncthreads();
  const float mx  = smx[0];
  const float mn  = smn[0];
  const float avg = ssm[0] * (1.0f / 1024.0f);
  const float den = 0.01f * (mx - mn);

  float4 rl;
  rl.x = 1.0f / (1.0f + expf((nm.x - avg) / den));
  rl.y = 1.0f / (1.0f + expf((nm.y - avg) / den));
  rl.z = 1.0f / (1.0f + expf((nm.z - avg) / den));
  rl.w = 1.0f / (1.0f + expf((nm.w - avg) / den));
  if (isnan(rl.x)) rl.x = 1.0f;
  if (isnan(rl.y)) rl.y = 1.0f;
  if (isnan(rl.z)) rl.z = 1.0f;
  if (isnan(rl.w)) rl.w = 1.0f;

  float4 nw;
  nw.x = wv4.x + 0.3f * (xv.x - wv4.x);
  nw.y = wv4.y + 0.3f * (xv.y - wv4.y);
  nw.z = wv4.z + 0.3f * (xv.z - wv4.z);
  nw.w = wv4.w + 0.3f * (xv.w - wv4.w);

  ((float4*)(out_w   + ro))[t] = nw;
  ((float4*)(out_ma  + ro))[t] = nm;
  ((float4*)(out_rel + ro))[t] = rl;
}

// ---------------- loss ----------------
__global__ __launch_bounds__(256) void loss_partial(
    const float* __restrict__ x, const float* __restrict__ w,
    const int* __restrict__ idx_int, double* __restrict__ partials) {
  const int t = threadIdx.x;
  double acc = 0.0;
  for (int b = blockIdx.x; b < B_DIM; b += gridDim.x) {
    int k = idx_int[b];
    float4 xv = ((const float4*)(x + (size_t)b * D_DIM))[t];
    float4 wv = ((const float4*)(w + (size_t)k * D_DIM))[t];
    float s = (xv.x - wv.x) + (xv.y - wv.y) + (xv.z - wv.z) + (xv.w - wv.w);
    acc += (double)s;
  }
  for (int m = 1; m < 64; m <<= 1) acc += __shfl_xor(acc, m, 64);
  __shared__ double sa[4];
  if ((t & 63) == 0) sa[t >> 6] = acc;
  __syncthreads();
  if (t == 0) partials[blockIdx.x] = sa[0] + sa[1] + sa[2] + sa[3];
}

__global__ void loss_final(const double* __restrict__ partials,
                           float* __restrict__ out_loss) {
  const int t = threadIdx.x;
  double acc = partials[t];
  for (int m = 1; m < 64; m <<= 1) acc += __shfl_xor(acc, m, 64);
  __shared__ double sa[4];
  if ((t & 63) == 0) sa[t >> 6] = acc;
  __syncthreads();
  if (t == 0)
    out_loss[0] = (float)(0.3 * (sa[0] + sa[1] + sa[2] + sa[3]) / (double)B_DIM);
}

// ---------------- fallback vector-ALU argmax (round-1 path) ----------------
__global__ __launch_bounds__(256) void prep_kernel(
    const float* __restrict__ x, const float* __restrict__ w,
    const float* __restrict__ rel,
    float* __restrict__ w_norm, float* __restrict__ rel_sum,
    float* __restrict__ x_norm) {
  int row  = blockIdx.x * 4 + (threadIdx.x >> 6);
  int lane = threadIdx.x & 63;
  if (row < K_DIM) {
    const float4* wr = (const float4*)(w   + (size_t)row * D_DIM);
    const float4* rr = (const float4*)(rel + (size_t)row * D_DIM);
    float s2 = 0.f, sr = 0.f;
#pragma unroll
    for (int q = 0; q < 4; ++q) {
      float4 wv = wr[lane + 64 * q];
      float4 rv = rr[lane + 64 * q];
      s2 += wv.x * wv.x + wv.y * wv.y + wv.z * wv.z + wv.w * wv.w;
      sr += rv.x + rv.y + rv.z + rv.w;
    }
    for (int m = 1; m < 64; m <<= 1) {
      s2 += __shfl_xor(s2, m, 64);
      sr += __shfl_xor(sr, m, 64);
    }
    if (lane == 0) { w_norm[row] = s2; rel_sum[row] = sr; }
  } else {
    int rb = row - K_DIM;
    const float4* xr = (const float4*)(x + (size_t)rb * D_DIM);
    float s2 = 0.f;
#pragma unroll
    for (int q = 0; q < 4; ++q) {
      float4 xv = xr[lane + 64 * q];
      s2 += xv.x * xv.x + xv.y * xv.y + xv.z * xv.z + xv.w * xv.w;
    }
    for (int m = 1; m < 64; m <<= 1) s2 += __shfl_xor(s2, m, 64);
    if (lane == 0) x_norm[rb] = s2;
  }
}

__global__ __launch_bounds__(256) void argmax_kernel(
    const float* __restrict__ x, const float* __restrict__ w,
    const float* __restrict__ w_norm, const float* __restrict__ rel_sum,
    const float* __restrict__ x_norm,
    float* __restrict__ pact, int* __restrict__ pidx) {
  __shared__ float xsT[16][68];
  __shared__ float wsT[16][68];
  const int tid = threadIdx.x;
  const int tx = tid & 15, ty = tid >> 4;
  const int row0 = blockIdx.x * 64;
  const int ks0  = blockIdx.y * KRANGE;

  float xn[4];
#pragma unroll
  for (int i = 0; i < 4; ++i) xn[i] = x_norm[row0 + ty * 4 + i];
  float bestA[4]; int bestI[4];
#pragma unroll
  for (int i = 0; i < 4; ++i) { bestA[i] = -INFINITY; bestI[i] = 0x7fffffff; }
  const int lr = tid >> 2;
  const int lc = (tid & 3) * 4;

  for (int kc = 0; kc < KRANGE; kc += 64) {
    const int k0 = ks0 + kc;
    float acc[4][4];
#pragma unroll
    for (int i = 0; i < 4; ++i)
#pragma unroll
      for (int j = 0; j < 4; ++j) acc[i][j] = 0.f;
    for (int d0 = 0; d0 < D_DIM; d0 += 16) {
      float4 xv = *(const float4*)(x + (size_t)(row0 + lr) * D_DIM + d0 + lc);
      float4 wv = *(const float4*)(w + (size_t)(k0  + lr) * D_DIM + d0 + lc);
      __syncthreads();
      xsT[lc + 0][lr] = xv.x; xsT[lc + 1][lr] = xv.y;
      xsT[lc + 2][lr] = xv.z; xsT[lc + 3][lr] = xv.w;
      wsT[lc + 0][lr] = wv.x; wsT[lc + 1][lr] = wv.y;
      wsT[lc + 2][lr] = wv.z; wsT[lc + 3][lr] = wv.w;
      __syncthreads();
#pragma unroll
      for (int kk = 0; kk < 16; ++kk) {
        float4 av = *(const float4*)&xsT[kk][ty * 4];
        float4 bv = *(const float4*)&wsT[kk][tx * 4];
        float ar[4] = {av.x, av.y, av.z, av.w};
        float br[4] = {bv.x, bv.y, bv.z, bv.w};
#pragma unroll
        for (int i = 0; i < 4; ++i)
#pragma unroll
          for (int j = 0; j < 4; ++j)
            acc[i][j] = fmaf(ar[i], br[j], acc[i][j]);
      }
    }
#pragma unroll
    for (int j = 0; j < 4; ++j) {
      int k = k0 + tx * 4 + j;
      float rs = rel_sum[k];
      float wn = w_norm[k];
      float rs_d = rs * (1.0f / 1024.0f);
#pragma unroll
      for (int i = 0; i < 4; ++i) {
        float dist = (xn[i] + wn) - 2.0f * acc[i][j];
        float dw   = dist * rs_d;
        float act  = rs / ((rs + dw) + 1e-7f);
        if (act > bestA[i] || (act == bestA[i] && k < bestI[i])) {
          bestA[i] = act; bestI[i] = k;
        }
      }
    }
  }
#pragma unroll
  for (int m = 1; m < 16; m <<= 1) {
#pragma unroll
    for (int i = 0; i < 4; ++i) {
      float oa = __shfl_xor(bestA[i], m, 64);
      int   oi = __shfl_xor(bestI[i], m, 64);
      if (oa > bestA[i] || (oa == bestA[i] && oi < bestI[i])) {
        bestA[i] = oa; bestI[i] = oi;
      }
    }
  }
  if (tx == 0) {
#pragma unroll
    for (int i = 0; i < 4; ++i) {
      int r = row0 + ty * 4 + i;
      pact[(size_t)r * NSPLIT_OLD + blockIdx.y] = bestA[i];
      pidx[(size_t)r * NSPLIT_OLD + blockIdx.y] = bestI[i];
    }
  }
}

__global__ void combine_kernel(const float* __restrict__ pact,
                               const int* __restrict__ pidx,
                               int* __restrict__ idx_int,
                               float* __restrict__ out_idx, int nsplit) {
  int b = blockIdx.x * 256 + threadIdx.x;
  if (b >= B_DIM) return;
  float bA = -INFINITY; int bI = 0x7fffffff;
  for (int s = 0; s < nsplit; ++s) {
    float a = pact[(size_t)b * nsplit + s];
    int  i2 = pidx[(size_t)b * nsplit + s];
    if (a > bA || (a == bA && i2 < bI)) { bA = a; bI = i2; }
  }
  idx_int[b] = bI;
  out_idx[b] = (float)bI;
}

__global__ void winner_kernel(const int* __restrict__ idx_int,
                              int* __restrict__ winner) {
  int b = blockIdx.x * 256 + threadIdx.x;
  if (b < B_DIM) atomicMax(&winner[idx_int[b]], b);
}

extern "C" void kernel_launch(void* const* d_in, const int* in_sizes, int n_in,
                              void* d_out, int out_size, void* d_ws, size_t ws_size,
                              hipStream_t stream) {
  const float* x   = (const float*)d_in[0];
  const float* w   = (const float*)d_in[1];
  const float* ma  = (const float*)d_in[2];
  const float* rel = (const float*)d_in[3];

  float* out      = (float*)d_out;
  float* out_loss = out;
  float* out_idx  = out + 1;
  float* out_w    = out + 1 + B_DIM;
  float* out_ma   = out_w  + (size_t)K_DIM * D_DIM;
  float* out_rel  = out_ma + (size_t)K_DIM * D_DIM;

  char* ws = (char*)d_ws;

  if (ws_size >= (size_t)N_NEED) {
    // -------- screen+refine path --------
    unsigned short* xh = (unsigned short*)(ws + N_XH);
    unsigned short* whp = (unsigned short*)(ws + N_WH);
    float* act_hi  = (float*)(ws + N_ACTHI);
    float* act_lo  = out_w;   // 48 MB of d_out, written before update_kernel
    float*  w_norm  = (float*)(ws + N_WN);
    float*  rel_sum = (float*)(ws + N_RS);
    float*  x_norm  = (float*)(ws + N_XN);
    float*  pact    = (float*)(ws + N_PACT);
    float*  rowmax  = (float*)(ws + N_RMX);
    int*    idx_int = (int*)  (ws + N_IDX);
    int*    winner  = (int*)  (ws + N_WIN);
    double* lparts  = (double*)(ws + N_LP);

    prep_convert_kernel<<<(K_DIM + B_DIM) / 4, 256, 0, stream>>>(
        x, w, rel, xh, whp, w_norm, rel_sum, x_norm);
    winner_init<<<K_DIM / 256, 256, 0, stream>>>(winner);
    mfma_act_kernel<<<dim3(B_DIM / 128, K_DIM / 128), 256, 0, stream>>>(
        xh, whp, w_norm, rel_sum, x_norm, act_lo, act_hi, pact);
    rowmax_kernel<<<B_DIM / 256, 256, 0, stream>>>(pact, rowmax);
    scan_refine_kernel<<<B_DIM, 256, 0, stream>>>(
        act_lo, act_hi, rowmax, x, w, w_norm, rel_sum, x_norm,
        idx_int, out_idx, winner);
    update_kernel<<<K_DIM, 256, 0, stream>>>(x, w, ma, rel, winner, out_w, out_ma, out_rel);
    loss_partial<<<256, 256, 0, stream>>>(x, w, idx_int, lparts);
    loss_final<<<1, 256, 0, stream>>>(lparts, out_loss);
  } else {
    // -------- fallback (round-1) path --------
    float*  w_norm  = (float*)(ws + WN_OFF);
    float*  rel_sum = (float*)(ws + RS_OFF);
    float*  x_norm  = (float*)(ws + XN_OFF);
    float*  pact    = (float*)(ws + PACT_OFF);
    int*    pidx    = (int*)  (ws + PIDX_OFF);
    int*    idx_int = (int*)  (ws + IDX_OFF);
    int*    winner  = (int*)  (ws + WIN_OFF);
    double* lparts  = (double*)(ws + LP_OFF);

    prep_kernel<<<(K_DIM + B_DIM) / 4, 256, 0, stream>>>(x, w, rel, w_norm, rel_sum, x_norm);
    winner_init<<<K_DIM / 256, 256, 0, stream>>>(winner);
    argmax_kernel<<<dim3(B_DIM / 64, NSPLIT_OLD), 256, 0, stream>>>(
        x, w, w_norm, rel_sum, x_norm, pact, pidx);
    combine_kernel<<<B_DIM / 256, 256, 0, stream>>>(pact, pidx, idx_int, out_idx, NSPLIT_OLD);
    winner_kernel<<<B_DIM / 256, 256, 0, stream>>>(idx_int, winner);
    update_kernel<<<K_DIM, 256, 0, stream>>>(x, w, ma, rel, winner, out_w, out_ma, out_rel);
    loss_partial<<<256, 256, 0, stream>>>(x, w, idx_int, lparts);
    loss_final<<<1, 256, 0, stream>>>(lparts, out_loss);
  }
}